// Round 10
// baseline (412.637 us; speedup 1.0000x reference)
//
#include <hip/hip_runtime.h>
#include <math.h>

#define NPTS 4096
#define BLK 256
#define V 32
#define NPROJ 256
#define NBATCH 32

// R16: two-wave-per-sort restructure — v[32] per thread, 128 threads/sort.
// R12-R15 invariant: with v[64]/thread the allocator ALWAYS parks the array
// in AGPRs (VGPR_Count 56/64/68 across occupancy targets 102/128/170; even
// "+v" inline-asm pins were satisfied with shuttles). Measured VALU-issue
// time ~210us vs ~90us instruction floor = multiplicative per-op inflation
// (accvgpr_read/write around compares). No knob changes the class split.
// Fix by construction: halve per-thread state. v[32] + ~20 temps ~= 52 regs
// fits even the allocator's most aggressive budget (8 waves/EU = 64 regs)
// in pure arch VGPRs — there is nothing left to shuttle.
// Bonus: occupancy LDS-bound at 5 blocks x 4 waves = 20 waves/CU (62%,
// ~5 waves/SIMD vs 2.5 before) -> shfl/crossbar latency finally hidden.
// Structure: block = 256 thr; sortid = tid>>7 (0: x, waves 0-1; 1: y, waves
// 2-3); T = tid&127 thread-in-sort; element idx = T*32 + r.
// Network (normalized bitonic, all runs ascending; keep side of merge m =
// idx bit log2(m), of cleaner j = idx bit log2(j)):
//   merges 2..32: in-reg (rev_inreg + stages)
//   merge 64..2048: rev_shfl32<(m/32-1)> + stage_shfl<j/32> chain + stages<16,1>
//     (all masks <= 63: in-wave; T bit k = lane bit k for k<6)
//   merge 4096: rev (partner T^127, regs reversed, keep = T bit 6 = wave half)
//     and cleaner j=2048 (partner T^64, keep = wave half) via 2 LDS trips on
//     a per-sort 16 KiB half (write_own / read_rev127 / read_j2048, XOR slot
//     placement slot=(T<<3)|(c^(T&7)) — conflict-free, verified family);
//     then in-wave stage_shfl<32..1> + stages<16,1>.
// 5 barriers total; y republishes final half; x fused-diff + 2 atomicAdds.

__device__ __forceinline__ void cmpex_asc(float& a, float& b) {
    const float lo = fminf(a, b), hi = fmaxf(a, b);
    a = lo; b = hi;
}

template<int JB, int JL>
__device__ __forceinline__ void stages(float* v) {
#pragma unroll
    for (int r = 0; r < V; ++r)
        if ((r & JB) == 0) cmpex_asc(v[r], v[r | JB]);
    if constexpr (JB > JL) stages<(JB >> 1), JL>(v);
}

template<int MASK>
__device__ __forceinline__ void rev_inreg(float* v) {
    constexpr int S = (MASK + 1) >> 1;
#pragma unroll
    for (int r = 0; r < V; ++r) {
        if ((r & S) == 0) {
            const float a = v[r], b = v[r ^ MASK];
            v[r] = fminf(a, b);
            v[r ^ MASK] = fmaxf(a, b);
        }
    }
}

// Keep-side select: hi lanes keep max, lo lanes keep min, of (mine, q).
// ((q < mine) != hi) ? q : mine == hi ? max : min (ties keep mine).
__device__ __forceinline__ float keep(float mine, float q, bool hi) {
    return ((q < mine) != hi) ? q : mine;
}

// Reversal across thread-pair (xor XM), registers reversed (r <-> 31-r).
template<int XM>
__device__ __forceinline__ void rev_shfl32(float* v, bool hi) {
#pragma unroll
    for (int r = 0; r < 16; ++r) {
        const float pa = __shfl_xor(v[31 - r], XM, 64);
        const float pb = __shfl_xor(v[r], XM, 64);
        v[r]      = keep(v[r],      pa, hi);
        v[31 - r] = keep(v[31 - r], pb, hi);
    }
}
// Same-register cross-thread stage (xor XM).
template<int XM>
__device__ __forceinline__ void stage_shfl(float* v, bool hi) {
#pragma unroll
    for (int r = 0; r < V; ++r) {
        const float q = __shfl_xor(v[r], XM, 64);
        v[r] = keep(v[r], q, hi);
    }
}

// LDS slot for (thread T, float4-chunk c): (T<<3)|(c^(T&7)).
// Per b128 instruction (fixed c): banks 4*(c^(T&7))+{0..3} spread over all
// 32 banks, 8 dwords/bank — conflict-free (same family as R12's verified 0).
__device__ __forceinline__ void write_own(float* s, const float* v, int T) {
    float4* s4 = (float4*)s;
    const int tb = T & 7;
#pragma unroll
    for (int c = 0; c < 8; ++c)
        s4[(T << 3) | (c ^ tb)] =
            make_float4(v[4*c], v[4*c+1], v[4*c+2], v[4*c+3]);
}
// m4096 reversal: partner T^127, partner reg 31-r (their chunk 7-c, comps
// reversed). keep side = own wave half w (idx bit 11 = T bit 6).
__device__ __forceinline__ void read_rev127(const float* s, float* v, int T, bool w) {
    const float4* s4 = (const float4*)s;
    const int pt = T ^ 127, pb = pt & 7;
#pragma unroll
    for (int c = 0; c < 8; ++c) {
        const float4 q = s4[(pt << 3) | ((7 - c) ^ pb)];
        v[4*c+0] = keep(v[4*c+0], q.w, w);
        v[4*c+1] = keep(v[4*c+1], q.z, w);
        v[4*c+2] = keep(v[4*c+2], q.y, w);
        v[4*c+3] = keep(v[4*c+3], q.x, w);
    }
}
// Cleaner j=2048: partner T^64, same reg. keep side = wave half w.
__device__ __forceinline__ void read_j2048(const float* s, float* v, int T, bool w) {
    const float4* s4 = (const float4*)s;
    const int pt = T ^ 64, pb = pt & 7;   // pb == T&7
#pragma unroll
    for (int c = 0; c < 8; ++c) {
        const float4 q = s4[(pt << 3) | (c ^ pb)];
        v[4*c+0] = keep(v[4*c+0], q.x, w);
        v[4*c+1] = keep(v[4*c+1], q.y, w);
        v[4*c+2] = keep(v[4*c+2], q.z, w);
        v[4*c+3] = keep(v[4*c+3], q.w, w);
    }
}

// Load 32 points (96 floats = 24 float4) and project onto (p0,p1,p2).
__device__ __forceinline__ void load_project(const float* base, float* v,
                                             float p0, float p1, float p2) {
    const float4* b4 = (const float4*)base;
#pragma unroll
    for (int g = 0; g < 8; ++g) {
        float4 a = b4[g * 3 + 0], c = b4[g * 3 + 1], d = b4[g * 3 + 2];
        v[4*g+0] = a.x * p0 + a.y * p1 + a.z * p2;
        v[4*g+1] = a.w * p0 + c.x * p1 + c.y * p2;
        v[4*g+2] = c.z * p0 + c.w * p1 + d.x * p2;
        v[4*g+3] = d.y * p0 + d.z * p1 + d.w * p2;
    }
}

__global__ __launch_bounds__(BLK) void swd_kernel(
    const float* __restrict__ x, const float* __restrict__ y,
    const float* __restrict__ theta, const float* __restrict__ rot,
    float* __restrict__ per_batch) {
    __shared__ float buf[2][NPTS];   // 32 KiB: one 16 KiB half per sort

    const int tid = threadIdx.x;
    const int sortid = tid >> 7;          // 0: x (waves 0-1), 1: y (waves 2-3)
    const int T = tid & 127;              // thread-in-sort
    const int t = tid & 63;               // wave lane (= T & 63)
    const bool w = (T & 64) != 0;         // wave half within sort (idx bit 11)
    const int p = blockIdx.x;
    const int b = blockIdx.y;

    const float t0 = theta[p * 3 + 0], t1 = theta[p * 3 + 1], t2 = theta[p * 3 + 2];
    const float* R = rot + b * 9;
    const float p0 = t0 * R[0] + t1 * R[3] + t2 * R[6];
    const float p1 = t0 * R[1] + t1 * R[4] + t2 * R[7];
    const float p2 = t0 * R[2] + t1 * R[5] + t2 * R[8];

    const float* src = sortid ? y : x;

    float v[V];
    load_project(src + (size_t)b * NPTS * 3 + (size_t)T * V * 3, v, p0, p1, p2);

    const bool h1  = (t & 1) != 0;
    const bool h2  = (t & 2) != 0;
    const bool h4  = (t & 4) != 0;
    const bool h8  = (t & 8) != 0;
    const bool h16 = (t & 16) != 0;
    const bool h32 = (t & 32) != 0;

    // merges 2..32: in-reg
    rev_inreg<1>(v);
    rev_inreg<3>(v);  stages<1, 1>(v);
    rev_inreg<7>(v);  stages<2, 1>(v);
    rev_inreg<15>(v); stages<4, 1>(v);
    rev_inreg<31>(v); stages<8, 1>(v);
    // merge 64: rev partner idx^63 = T^1 (keep bit 5 = T bit 0)
    rev_shfl32<1>(v, h1);
    stages<16, 1>(v);
    // merge 128: rev T^3 (keep T bit 1); j=32: T^1 (T bit 0)
    rev_shfl32<3>(v, h2);
    stage_shfl<1>(v, h1);
    stages<16, 1>(v);
    // merge 256: rev T^7 (T bit 2); j=64: T^2; j=32: T^1
    rev_shfl32<7>(v, h4);
    stage_shfl<2>(v, h2);
    stage_shfl<1>(v, h1);
    stages<16, 1>(v);
    // merge 512: rev T^15 (T bit 3); j=128: T^4; 64: T^2; 32: T^1
    rev_shfl32<15>(v, h8);
    stage_shfl<4>(v, h4);
    stage_shfl<2>(v, h2);
    stage_shfl<1>(v, h1);
    stages<16, 1>(v);
    // merge 1024: rev T^31 (T bit 4); j=256: T^8; ...
    rev_shfl32<31>(v, h16);
    stage_shfl<8>(v, h8);
    stage_shfl<4>(v, h4);
    stage_shfl<2>(v, h2);
    stage_shfl<1>(v, h1);
    stages<16, 1>(v);
    // merge 2048: rev T^63 (T bit 5); j=512: T^16; ...
    rev_shfl32<63>(v, h32);
    stage_shfl<16>(v, h16);
    stage_shfl<8>(v, h8);
    stage_shfl<4>(v, h4);
    stage_shfl<2>(v, h2);
    stage_shfl<1>(v, h1);
    stages<16, 1>(v);

    // merge 4096: cross-wave rev (T^127) and j=2048 (T^64) via LDS trips.
    float* half = buf[sortid];
    write_own(half, v, T);
    __syncthreads();
    read_rev127(half, v, T, w);
    __syncthreads();
    write_own(half, v, T);
    __syncthreads();
    read_j2048(half, v, T, w);
    // in-wave cleaners: j=1024: T^32 (keep T bit 5); 512: T^16; ...; 32: T^1
    stage_shfl<32>(v, h32);
    stage_shfl<16>(v, h16);
    stage_shfl<8>(v, h8);
    stage_shfl<4>(v, h4);
    stage_shfl<2>(v, h2);
    stage_shfl<1>(v, h1);
    stages<16, 1>(v);

    // Publish final sorted y; x diffs.
    __syncthreads();                 // all trip reads done; halves reusable
    if (sortid == 1) write_own(buf[1], v, T);
    __syncthreads();

    if (sortid == 0) {
        const float4* s4 = (const float4*)buf[1];
        const int tb = T & 7;
        float s = 0.0f;
#pragma unroll
        for (int c = 0; c < 8; ++c) {
            const float4 f = s4[(T << 3) | (c ^ tb)];
            const float d0 = v[4*c+0] - f.x;
            const float d1 = v[4*c+1] - f.y;
            const float d2 = v[4*c+2] - f.z;
            const float d3 = v[4*c+3] - f.w;
            s += d0 * d0 + d1 * d1 + d2 * d2 + d3 * d3;
        }
        for (int off = 32; off > 0; off >>= 1) s += __shfl_down(s, off, 64);
        if (t == 0) atomicAdd(&per_batch[b], s);   // waves 0 and 1: 2 adds
    }
}

__global__ void finalize_kernel(const float* __restrict__ per_batch, float* __restrict__ out) {
    const int t = threadIdx.x;  // 64 threads
    float v = (t < NBATCH) ? sqrtf(per_batch[t] * (1.0f / (float)NPROJ)) : 0.0f;
    for (int off = 32; off > 0; off >>= 1) v += __shfl_down(v, off, 64);
    if (t == 0) out[0] = v * (1.0f / (float)NBATCH);
}

extern "C" void kernel_launch(void* const* d_in, const int* in_sizes, int n_in,
                              void* d_out, int out_size, void* d_ws, size_t ws_size,
                              hipStream_t stream) {
    const float* x = (const float*)d_in[0];
    const float* y = (const float*)d_in[1];
    const float* theta = (const float*)d_in[2];
    const float* rot = (const float*)d_in[3];
    float* per_batch = (float*)d_ws;
    float* out = (float*)d_out;

    hipMemsetAsync(per_batch, 0, NBATCH * sizeof(float), stream);

    dim3 grid(NPROJ, NBATCH);
    swd_kernel<<<grid, BLK, 0, stream>>>(x, y, theta, rot, per_batch);

    finalize_kernel<<<1, 64, 0, stream>>>(per_batch, out);
}

// Round 11
// 360.324 us; speedup vs baseline: 1.1452x; 1.1452x over previous
//
#include <hip/hip_runtime.h>
#include <math.h>

#define NPTS 4096
#define BLK 128
#define V 64
#define NPROJ 256
#define NBATCH 32

// R17: R13's LDS-free shfl-bitonic + sched_barrier(0) fences inside the
// shfl stages — attacking the CAUSE of the AGPR parking, not the symptom.
// Six-round synthesis:
//   R8 (pre-shfl): VGPR_Count 84 = v[64]+20 temps, arch-resident, no tax.
//   R12-R16 (shfl): VGPR_Count 48-68 at every occupancy target (102/128/170)
//   — the unrolled rev_shfl/stage_shfl let the pre-RA scheduler hoist up to
//   64 ds_swizzle results to hide LDS latency -> peak pressure ~140 >
//   allocator's ~102 target -> array parked in acc half; every in-reg cmpex
//   then costs ~6 VALU (2 accvgpr_read + min + max + 2 accvgpr_write) vs 2.
//   Measured: VALU-busy 208-222us vs ~90-115us op floor across R13-R16 —
//   a uniform ~2.3x per-op multiplier = the shuttle signature.
// Fix: __builtin_amdgcn_sched_barrier(0) every 4 elems in rev_shfl / 8 in
// stage_shfl. Compile-time scheduling fence, zero instructions: caps live
// shfl temps at ~8 -> peak pressure ~90 < 102 -> allocator keeps the array
// architectural. Inter-wave parallelism (3-4 waves/SIMD) hides the ds
// latency the scheduler can no longer overlap intra-wave.
// Config: launch_bounds(128,2) (R12's), no waves_per_eu attr.
// Network unchanged (verified absmax 0.0 since R12): layout A
// (idx = lane*64 + reg); merges 2..64 in-reg; merge m>=128:
// rev_shfl<(m-1)>>6> + stage_shfl<j>>6> (j=m/4..64) + stages<32,1>.
// keep() = branchless compare-select (2 VALU). LDS = 16 KiB publish buffer.

__device__ __forceinline__ void cmpex_asc(float& a, float& b) {
    const float lo = fminf(a, b), hi = fmaxf(a, b);
    a = lo; b = hi;
}

template<int JB, int JL>
__device__ __forceinline__ void stages(float* v) {
#pragma unroll
    for (int r = 0; r < V; ++r)
        if ((r & JB) == 0) cmpex_asc(v[r], v[r | JB]);
    if constexpr (JB > JL) stages<(JB >> 1), JL>(v);
}

template<int MASK>
__device__ __forceinline__ void rev_inreg(float* v) {
    constexpr int S = (MASK + 1) >> 1;
#pragma unroll
    for (int r = 0; r < V; ++r) {
        if ((r & S) == 0) {
            const float a = v[r], b = v[r ^ MASK];
            v[r] = fminf(a, b);
            v[r ^ MASK] = fmaxf(a, b);
        }
    }
}

// Keep-side select: hi lanes keep max, lo lanes keep min, of (mine, q).
// ((q < mine) != hi) ? q : mine  ==  hi ? max : min  (ties keep mine).
// Branchless: v_cmp + mask-xor + v_cndmask.
__device__ __forceinline__ float keep(float mine, float q, bool hi) {
    return ((q < mine) != hi) ? q : mine;
}

// Reversal across thread-pair (xor XM), registers reversed (r <-> 63-r).
// sched_barrier every 4 elements: caps live shfl temps -> keeps register
// pressure under the allocator's occupancy target (see header).
template<int XM>
__device__ __forceinline__ void rev_shfl(float* v, bool hi) {
#pragma unroll
    for (int r = 0; r < 32; ++r) {
        const float pa = __shfl_xor(v[63 - r], XM, 64);
        const float pb = __shfl_xor(v[r], XM, 64);
        v[r]      = keep(v[r],      pa, hi);
        v[63 - r] = keep(v[63 - r], pb, hi);
        if ((r & 1) == 1) __builtin_amdgcn_sched_barrier(0);
    }
}
// Same-register cross-thread stage (xor XM).
template<int XM>
__device__ __forceinline__ void stage_shfl(float* v, bool hi) {
#pragma unroll
    for (int r = 0; r < V; ++r) {
        const float q = __shfl_xor(v[r], XM, 64);
        v[r] = keep(v[r], q, hi);
        if ((r & 3) == 3) __builtin_amdgcn_sched_barrier(0);
    }
}

// Natural (own-slot) publish write, float4-slot = (t<<4)|(c^t15)
// (bank-spreading XOR placement: conflict-free, verified 0 since R12).
__device__ __forceinline__ void write_own(float* s, const float* v, int t, int t15) {
    float4* s4 = (float4*)s;
#pragma unroll
    for (int c = 0; c < 16; ++c)
        s4[(t << 4) | (c ^ t15)] =
            make_float4(v[4*c], v[4*c+1], v[4*c+2], v[4*c+3]);
}

__device__ __forceinline__ void load_project(const float* base, float* v,
                                             float p0, float p1, float p2) {
    const float4* b4 = (const float4*)base;
#pragma unroll
    for (int g = 0; g < 16; ++g) {
        float4 a = b4[g * 3 + 0], c = b4[g * 3 + 1], d = b4[g * 3 + 2];
        v[4*g+0] = a.x * p0 + a.y * p1 + a.z * p2;
        v[4*g+1] = a.w * p0 + c.x * p1 + c.y * p2;
        v[4*g+2] = c.z * p0 + c.w * p1 + d.x * p2;
        v[4*g+3] = d.y * p0 + d.z * p1 + d.w * p2;
    }
}

// Full ascending sort of 4096 floats held as v[64] per thread, layout A
// (element idx = t*64 + r). Pure in-register + cross-lane; no LDS.
__device__ __forceinline__ void sort4096(float* v, int t) {
    const bool hi1  = (t & 1) != 0;
    const bool hi2  = (t & 2) != 0;
    const bool hi4  = (t & 4) != 0;
    const bool hi8  = (t & 8) != 0;
    const bool hi16 = (t & 16) != 0;
    const bool hi32 = (t & 32) != 0;

    // merges 2..64: fully in-register
    rev_inreg<1>(v);
    rev_inreg<3>(v);  stages<1, 1>(v);
    rev_inreg<7>(v);  stages<2, 1>(v);
    rev_inreg<15>(v); stages<4, 1>(v);
    rev_inreg<31>(v); stages<8, 1>(v);
    rev_inreg<63>(v); stages<16, 1>(v);

    // merge 128
    rev_shfl<1>(v, hi1);
    stages<32, 1>(v);

    // merge 256
    rev_shfl<3>(v, hi2);
    stage_shfl<2>(v, hi2);
    stage_shfl<1>(v, hi1);
    stages<32, 1>(v);

    // merge 512
    rev_shfl<7>(v, hi4);
    stage_shfl<2>(v, hi2);
    stage_shfl<1>(v, hi1);
    stages<32, 1>(v);

    // merge 1024
    rev_shfl<15>(v, hi8);
    stage_shfl<4>(v, hi4);
    stage_shfl<2>(v, hi2);
    stage_shfl<1>(v, hi1);
    stages<32, 1>(v);

    // merge 2048
    rev_shfl<31>(v, hi16);
    stage_shfl<8>(v, hi8);
    stage_shfl<4>(v, hi4);
    stage_shfl<2>(v, hi2);
    stage_shfl<1>(v, hi1);
    stages<32, 1>(v);

    // merge 4096
    rev_shfl<63>(v, hi32);
    stage_shfl<16>(v, hi16);
    stage_shfl<8>(v, hi8);
    stage_shfl<4>(v, hi4);
    stage_shfl<2>(v, hi2);
    stage_shfl<1>(v, hi1);
    stages<32, 1>(v);
}

__global__ __launch_bounds__(BLK, 2) void swd_kernel(
    const float* __restrict__ x, const float* __restrict__ y,
    const float* __restrict__ theta, const float* __restrict__ rot,
    float* __restrict__ per_batch) {
    __shared__ float buf[NPTS];   // 16 KiB — publish buffer only

    const int t = threadIdx.x & 63;       // wave lane
    const int wave = threadIdx.x >> 6;    // 0: x, 1: y
    const int p = blockIdx.x;
    const int b = blockIdx.y;

    const float t0 = theta[p * 3 + 0], t1 = theta[p * 3 + 1], t2 = theta[p * 3 + 2];
    const float* R = rot + b * 9;
    const float p0 = t0 * R[0] + t1 * R[3] + t2 * R[6];
    const float p1 = t0 * R[1] + t1 * R[4] + t2 * R[7];
    const float p2 = t0 * R[2] + t1 * R[5] + t2 * R[8];

    const float* src = wave ? y : x;

    // Each wave sorts its own array, completely barrier- and LDS-free.
    float v[V];
    load_project(src + (size_t)b * NPTS * 3 + (size_t)t * V * 3, v, p0, p1, p2);
    sort4096(v, t);

    const int t15 = t & 15;
    // Wave 1 publishes sorted y; wave 0 then diffs.
    if (wave == 1) write_own(buf, v, t, t15);
    __syncthreads();

    if (wave == 0) {
        // Fused read+diff: w never materializes.
        const float4* s4 = (const float4*)buf;
        float s = 0.0f;
#pragma unroll
        for (int c = 0; c < 16; ++c) {
            const float4 f = s4[(t << 4) | (c ^ t15)];
            const float d0 = v[4*c+0] - f.x;
            const float d1 = v[4*c+1] - f.y;
            const float d2 = v[4*c+2] - f.z;
            const float d3 = v[4*c+3] - f.w;
            s += d0 * d0 + d1 * d1 + d2 * d2 + d3 * d3;
        }
        for (int off = 32; off > 0; off >>= 1) s += __shfl_down(s, off, 64);
        if (t == 0) atomicAdd(&per_batch[b], s);
    }
}

__global__ void finalize_kernel(const float* __restrict__ per_batch, float* __restrict__ out) {
    const int t = threadIdx.x;  // 64 threads
    float v = (t < NBATCH) ? sqrtf(per_batch[t] * (1.0f / (float)NPROJ)) : 0.0f;
    for (int off = 32; off > 0; off >>= 1) v += __shfl_down(v, off, 64);
    if (t == 0) out[0] = v * (1.0f / (float)NBATCH);
}

extern "C" void kernel_launch(void* const* d_in, const int* in_sizes, int n_in,
                              void* d_out, int out_size, void* d_ws, size_t ws_size,
                              hipStream_t stream) {
    const float* x = (const float*)d_in[0];
    const float* y = (const float*)d_in[1];
    const float* theta = (const float*)d_in[2];
    const float* rot = (const float*)d_in[3];
    float* per_batch = (float*)d_ws;
    float* out = (float*)d_out;

    hipMemsetAsync(per_batch, 0, NBATCH * sizeof(float), stream);

    dim3 grid(NPROJ, NBATCH);
    swd_kernel<<<grid, BLK, 0, stream>>>(x, y, theta, rot, per_batch);

    finalize_kernel<<<1, 64, 0, stream>>>(per_batch, out);
}